// Round 2
// baseline (96.105 us; speedup 1.0000x reference)
//
#include <hip/hip_runtime.h>
#include <hip/hip_bf16.h>

// Problem: N=64, K=512, D=256. Reference reduces to out = relu(x @ W^T + b):
// softmax over j sums to 1 and einsum 'nkj,nkd->nkd' multiplies h by that sum.
// [32768,256] x [256,256]^T GEMM + bias + ReLU. Memory-bound (~67 MB HBM).
//
// R1..R6 history: register-B (42us) -> LDS W-slice (35us) -> coalesced
// staging (29us) -> persistent full-W LDS, x read once (17us) -> lgkm-only
// barriers + 2-deep prefetch (R6, ~17us kernel, 90-92us harness headline;
// headline includes ~85us of harness fillBuffer poisoning we don't control).
//
// R8 (this round): observation — wave w only ever reads ITS OWN 32 rows of
// W (bp = lw[(wave*32+ln)*LWS + ...]). The 132 KB full-W LDS + cooperative
// staging barrier bought nothing. So:
//   * B-operand in registers: 16 x bf16x8 = 64 VGPR per lane, self-staged
//     per wave from global (L3-resident, 256 KB total) with no barrier.
//   * lx ping-pong double-buffer (2 x 16.5 KB = 33 KB LDS total):
//     ONE lgkm-only barrier per tile instead of two (7 barriers -> 4).
//   * 3-deep x prefetch (Pa/Pb/Pc): whole read stream issued by tile 1,
//     overlapping HBM reads with nt-store drain across all 4 tiles.
// Predicted: kernel ~17 -> ~12-13us; LDS 152K -> 33.8K; bank conflicts 0.

#define DD 256          // feature dim
#define M_TOTAL 32768   // N*K rows
#define LWS 264         // LDS row stride in shorts (528 B): measured 0 conflicts

typedef short bf16x8 __attribute__((ext_vector_type(8)));
typedef float floatx16 __attribute__((ext_vector_type(16)));

// Barrier with LDS-only drain: does NOT wait vmcnt, so global prefetch
// loads and nontemporal stores stay in flight across it.
#define BAR() asm volatile("s_waitcnt lgkmcnt(0)\n\ts_barrier" ::: "memory")

// Pack 8 fp32 -> 8 bf16 (packed cvt, RNE).
__device__ inline bf16x8 pack8(float4 p0, float4 p1) {
    __hip_bfloat162 q0 = __float22bfloat162_rn(make_float2(p0.x, p0.y));
    __hip_bfloat162 q1 = __float22bfloat162_rn(make_float2(p0.z, p0.w));
    __hip_bfloat162 q2 = __float22bfloat162_rn(make_float2(p1.x, p1.y));
    __hip_bfloat162 q3 = __float22bfloat162_rn(make_float2(p1.z, p1.w));
    union { bf16x8 v; unsigned u[4]; } r;
    union { __hip_bfloat162 h; unsigned u; } c;
    c.h = q0; r.u[0] = c.u;
    c.h = q1; r.u[1] = c.u;
    c.h = q2; r.u[2] = c.u;
    c.h = q3; r.u[3] = c.u;
    return r.v;
}

// Each thread's share of one 32-row x tile: rows r0 and r0+16, 8 floats at c0.
__device__ inline void load_tile(const float* __restrict__ x, int m0,
                                 int r0, int c0, float4 P[4]) {
    const float* s0 = x + (m0 + r0) * DD + c0;
    const float* s1 = x + (m0 + 16 + r0) * DD + c0;
    P[0] = *(const float4*)(s0);
    P[1] = *(const float4*)(s0 + 4);
    P[2] = *(const float4*)(s1);
    P[3] = *(const float4*)(s1 + 4);
}

__device__ inline void write_lx(unsigned short* lx, int r0, int c0,
                                const float4 P[4]) {
    *(bf16x8*)(lx + r0 * LWS + c0)        = pack8(P[0], P[1]);
    *(bf16x8*)(lx + (16 + r0) * LWS + c0) = pack8(P[2], P[3]);
}

// A from LDS, B from registers (wave-private W strip).
__device__ inline void compute_tile(const unsigned short* ap,
                                    const bf16x8 (&B)[16], floatx16& acc) {
#pragma unroll
    for (int i = 0; i < 16; ++i) acc[i] = 0.f;
#pragma unroll
    for (int s = 0; s < 16; ++s) {
        bf16x8 af = *(const bf16x8*)(ap + s * 16);
        acc = __builtin_amdgcn_mfma_f32_32x32x16_bf16(af, B[s], acc, 0, 0, 0);
    }
}

// C/D layout: col = lane&31, row = (reg&3) + 8*(reg>>2) + 4*(lane>>5)
__device__ inline void store_tile(float* ob, int m0, int lh, float bias,
                                  const floatx16& acc) {
#pragma unroll
    for (int r = 0; r < 16; ++r) {
        const int m = m0 + (r & 3) + 8 * (r >> 2) + 4 * lh;
        float v = acc[r] + bias;
        v = v > 0.f ? v : 0.f;
        __builtin_nontemporal_store(v, ob + m * DD);
    }
}

// 512 thr = 8 waves; wave w owns e-strip [w*32, w*32+32). Block owns 128
// contiguous m-rows = 4 tiles of 32. Grid = 256 (1 block/CU).
__global__ void __launch_bounds__(512, 1)
fcgat_gemm(const float* __restrict__ x, const float* __restrict__ W,
           const float* __restrict__ Wbias, float* __restrict__ out) {
    __shared__ __align__(16) unsigned short lxbuf[2 * 32 * LWS];  // 33 KB

    const int tid   = threadIdx.x;        // 0..511
    const int r0    = tid >> 5;           // 0..15 (staging row base)
    const int c0    = (tid & 31) * 8;     // staging col (floats/shorts)
    const int mbase = blockIdx.x * 128;

    const int lane = tid & 63;
    const int wave = tid >> 6;            // 0..7 -> e-strip
    const int ln   = lane & 31;
    const int lh   = lane >> 5;           // k-half (0/1)

    unsigned short* lx0 = lxbuf;
    unsigned short* lx1 = lxbuf + 32 * LWS;

    // ---- issue tiles 0..2 prefetch FIRST (HBM stream starts immediately) --
    float4 Pa[4], Pb[4], Pc[4];
    load_tile(x, mbase + 0,  r0, c0, Pa);
    load_tile(x, mbase + 32, r0, c0, Pb);
    load_tile(x, mbase + 64, r0, c0, Pc);

    // ---- self-stage this wave's 32-row W strip into registers (no barrier).
    // B[s] = bf16(W[wave*32+ln][lh*8 + s*16 .. +8]) — identical fragments to
    // the old LDS path. ~512 B/lane from L3-resident W.
    bf16x8 B[16];
    {
        const float* wbase = W + (wave * 32 + ln) * DD + lh * 8;
#pragma unroll
        for (int s = 0; s < 16; ++s) {
            float4 w0 = *(const float4*)(wbase + s * 16);
            float4 w1 = *(const float4*)(wbase + s * 16 + 4);
            B[s] = pack8(w0, w1);
        }
    }

    const unsigned short* ap0 = lx0 + ln * LWS + lh * 8;
    const unsigned short* ap1 = lx1 + ln * LWS + lh * 8;
    const float bias = Wbias[wave * 32 + ln];
    float* ob = out + wave * 32 + ln;

    write_lx(lx0, r0, c0, Pa);            // waits only Pa's loads (fine vmcnt)
    BAR();                                // lx0 ready

    floatx16 acc;

    // ---- tile 0 ----
    load_tile(x, mbase + 96, r0, c0, Pa); // t3 into freed regs
    compute_tile(ap0, B, acc);
    write_lx(lx1, r0, c0, Pb);            // stage t1 (no reader of lx1 yet)
    store_tile(ob, mbase + 0, lh, bias, acc);
    BAR();                                // lx1 ready; lx0 free

    // ---- tile 1 ----
    compute_tile(ap1, B, acc);
    write_lx(lx0, r0, c0, Pc);            // stage t2
    store_tile(ob, mbase + 32, lh, bias, acc);
    BAR();                                // lx0 ready; lx1 free

    // ---- tile 2 ----
    compute_tile(ap0, B, acc);
    write_lx(lx1, r0, c0, Pa);            // stage t3
    store_tile(ob, mbase + 64, lh, bias, acc);
    BAR();                                // lx1 ready

    // ---- tile 3 ----
    compute_tile(ap1, B, acc);
    store_tile(ob, mbase + 96, lh, bias, acc);
}

extern "C" void kernel_launch(void* const* d_in, const int* in_sizes, int n_in,
                              void* d_out, int out_size, void* d_ws, size_t ws_size,
                              hipStream_t stream) {
    const float* x    = (const float*)d_in[0];  // [64,512,256]
    const float* W_w  = (const float*)d_in[1];  // [256,256]
    const float* W_b  = (const float*)d_in[2];  // [256]
    // d_in[3] = att_w, d_in[4] = att_b — provably unused (softmax sums to 1)
    float* out = (float*)d_out;                 // [64,512,256] fp32

    fcgat_gemm<<<M_TOTAL / 128, 512, 0, stream>>>(x, W_w, W_b, out);
}

// Round 3
// 89.945 us; speedup vs baseline: 1.0685x; 1.0685x over previous
//
#include <hip/hip_runtime.h>
#include <hip/hip_bf16.h>

// Problem: N=64, K=512, D=256. Reference reduces to out = relu(x @ W^T + b):
// softmax over j sums to 1 and einsum 'nkj,nkd->nkd' multiplies h by that sum.
// [32768,256] x [256,256]^T GEMM + bias + ReLU. Memory-bound (~67 MB HBM).
//
// R1..R6: register-B (42us) -> LDS W-slice (35us) -> coalesced staging
// (29us) -> persistent full-W LDS, x read once (~17us) -> lgkm-only barriers
// + 2-deep prefetch (R6; headline 90-92us incl. ~75us harness fill overhead).
// R8: B in regs, self-staged SCATTERED from global (lane-private 16B reads at
//     1KB stride = 4x L2 request amplification on W) + ping-pong lx.
//     Headline 96.1 (+4): the scattered W prologue stall beat the barrier
//     savings. Main-loop structure (1 barrier/tile, register-B) is sound.
// R9 (this round): hybrid. W staged cooperatively (coalesced, R6-proven) into
//     a 132 KB LDS buffer, each wave then reads ITS OWN 32-row strip into
//     B[16] registers via the 0-conflict ds_read_b128 layout; the W buffer's
//     first 33 KB is then REUSED as the lx ping-pong (W-LDS dead after reg
//     read). Main loop = R8: one lgkm-only barrier per tile, register B,
//     3-deep x prefetch, nt-stores never drained by barriers.
// Predicted: headline ~88-90us; LDS 135K; bank conflicts ~0; FETCH/WRITE
// unchanged (~34 MB each).

#define DD 256          // feature dim
#define M_TOTAL 32768   // N*K rows
#define LWS 264         // LDS row stride in shorts (528 B): measured 0 conflicts

typedef short bf16x8 __attribute__((ext_vector_type(8)));
typedef float floatx16 __attribute__((ext_vector_type(16)));

// Barrier with LDS-only drain: does NOT wait vmcnt, so global prefetch
// loads and nontemporal stores stay in flight across it.
#define BAR() asm volatile("s_waitcnt lgkmcnt(0)\n\ts_barrier" ::: "memory")

// Pack 8 fp32 -> 8 bf16 (packed cvt, RNE).
__device__ inline bf16x8 pack8(float4 p0, float4 p1) {
    __hip_bfloat162 q0 = __float22bfloat162_rn(make_float2(p0.x, p0.y));
    __hip_bfloat162 q1 = __float22bfloat162_rn(make_float2(p0.z, p0.w));
    __hip_bfloat162 q2 = __float22bfloat162_rn(make_float2(p1.x, p1.y));
    __hip_bfloat162 q3 = __float22bfloat162_rn(make_float2(p1.z, p1.w));
    union { bf16x8 v; unsigned u[4]; } r;
    union { __hip_bfloat162 h; unsigned u; } c;
    c.h = q0; r.u[0] = c.u;
    c.h = q1; r.u[1] = c.u;
    c.h = q2; r.u[2] = c.u;
    c.h = q3; r.u[3] = c.u;
    return r.v;
}

// Each thread's share of one 32-row x tile: rows r0 and r0+16, 8 floats at c0.
__device__ inline void load_tile(const float* __restrict__ x, int m0,
                                 int r0, int c0, float4 P[4]) {
    const float* s0 = x + (m0 + r0) * DD + c0;
    const float* s1 = x + (m0 + 16 + r0) * DD + c0;
    P[0] = *(const float4*)(s0);
    P[1] = *(const float4*)(s0 + 4);
    P[2] = *(const float4*)(s1);
    P[3] = *(const float4*)(s1 + 4);
}

__device__ inline void write_lx(unsigned short* lx, int r0, int c0,
                                const float4 P[4]) {
    *(bf16x8*)(lx + r0 * LWS + c0)        = pack8(P[0], P[1]);
    *(bf16x8*)(lx + (16 + r0) * LWS + c0) = pack8(P[2], P[3]);
}

// A from LDS, B from registers (wave-private W strip).
__device__ inline void compute_tile(const unsigned short* ap,
                                    const bf16x8 (&B)[16], floatx16& acc) {
#pragma unroll
    for (int i = 0; i < 16; ++i) acc[i] = 0.f;
#pragma unroll
    for (int s = 0; s < 16; ++s) {
        bf16x8 af = *(const bf16x8*)(ap + s * 16);
        acc = __builtin_amdgcn_mfma_f32_32x32x16_bf16(af, B[s], acc, 0, 0, 0);
    }
}

// C/D layout: col = lane&31, row = (reg&3) + 8*(reg>>2) + 4*(lane>>5)
__device__ inline void store_tile(float* ob, int m0, int lh, float bias,
                                  const floatx16& acc) {
#pragma unroll
    for (int r = 0; r < 16; ++r) {
        const int m = m0 + (r & 3) + 8 * (r >> 2) + 4 * lh;
        float v = acc[r] + bias;
        v = v > 0.f ? v : 0.f;
        __builtin_nontemporal_store(v, ob + m * DD);
    }
}

// 512 thr = 8 waves; wave w owns e-strip [w*32, w*32+32). Block owns 128
// contiguous m-rows = 4 tiles of 32. Grid = 256 (1 block/CU).
__global__ void __launch_bounds__(512, 1)
fcgat_gemm(const float* __restrict__ x, const float* __restrict__ W,
           const float* __restrict__ Wbias, float* __restrict__ out) {
    // 132 KB: W staging for the prologue; first 33 KB reused as lx ping-pong
    // for the main loop (W-LDS is dead once B[] is in registers).
    __shared__ __align__(16) unsigned short lw[256 * LWS];

    const int tid   = threadIdx.x;        // 0..511
    const int r0    = tid >> 5;           // 0..15 (staging row base)
    const int c0    = (tid & 31) * 8;     // staging col (floats/shorts)
    const int mbase = blockIdx.x * 128;

    const int lane = tid & 63;
    const int wave = tid >> 6;            // 0..7 -> e-strip
    const int ln   = lane & 31;
    const int lh   = lane >> 5;           // k-half (0/1)

    unsigned short* lx0 = lw;
    unsigned short* lx1 = lw + 32 * LWS;

    // ---- issue tiles 0..2 x-prefetch FIRST (HBM stream starts now, stays
    // in flight through the whole W prologue) --------------------------------
    float4 Pa[4], Pb[4], Pc[4];
    load_tile(x, mbase + 0,  r0, c0, Pa);
    load_tile(x, mbase + 32, r0, c0, Pb);
    load_tile(x, mbase + 64, r0, c0, Pc);

    // ---- stage full W fp32 -> bf16 -> LDS, COALESCED (32 lanes = 1 row) ---
#pragma unroll
    for (int k = 0; k < 16; ++k) {
        const int r = r0 + 16 * k;        // 0..255
        const float* ws = W + r * DD + c0;
        float4 a0 = *(const float4*)(ws);
        float4 a1 = *(const float4*)(ws + 4);
        *(bf16x8*)(lw + r * LWS + c0) = pack8(a0, a1);
    }
    BAR();                                // W visible to all waves

    // ---- each wave pulls ITS OWN 32-row W strip into registers ------------
    // (ds_read_b128 at the measured-0-conflict LWS=264 layout; ~16 reads/lane)
    bf16x8 B[16];
    {
        const unsigned short* bp = lw + (wave * 32 + ln) * LWS + lh * 8;
#pragma unroll
        for (int s = 0; s < 16; ++s) B[s] = *(const bf16x8*)(bp + s * 16);
    }
    BAR();                                // all B-reads retired before lx reuse

    const unsigned short* ap0 = lx0 + ln * LWS + lh * 8;
    const unsigned short* ap1 = lx1 + ln * LWS + lh * 8;
    const float bias = Wbias[wave * 32 + ln];
    float* ob = out + wave * 32 + ln;

    write_lx(lx0, r0, c0, Pa);            // waits only Pa's loads (fine vmcnt)
    BAR();                                // lx0 ready

    floatx16 acc;

    // ---- tile 0 ----
    load_tile(x, mbase + 96, r0, c0, Pa); // t3 into freed regs
    compute_tile(ap0, B, acc);
    write_lx(lx1, r0, c0, Pb);            // stage t1 (lx1 has no reader yet)
    store_tile(ob, mbase + 0, lh, bias, acc);
    BAR();                                // lx1 ready; lx0 free

    // ---- tile 1 ----
    compute_tile(ap1, B, acc);
    write_lx(lx0, r0, c0, Pc);            // stage t2
    store_tile(ob, mbase + 32, lh, bias, acc);
    BAR();                                // lx0 ready; lx1 free

    // ---- tile 2 ----
    compute_tile(ap0, B, acc);
    write_lx(lx1, r0, c0, Pa);            // stage t3
    store_tile(ob, mbase + 64, lh, bias, acc);
    BAR();                                // lx1 ready

    // ---- tile 3 ----
    compute_tile(ap1, B, acc);
    store_tile(ob, mbase + 96, lh, bias, acc);
}

extern "C" void kernel_launch(void* const* d_in, const int* in_sizes, int n_in,
                              void* d_out, int out_size, void* d_ws, size_t ws_size,
                              hipStream_t stream) {
    const float* x    = (const float*)d_in[0];  // [64,512,256]
    const float* W_w  = (const float*)d_in[1];  // [256,256]
    const float* W_b  = (const float*)d_in[2];  // [256]
    // d_in[3] = att_w, d_in[4] = att_b — provably unused (softmax sums to 1)
    float* out = (float*)d_out;                 // [64,512,256] fp32

    fcgat_gemm<<<M_TOTAL / 128, 512, 0, stream>>>(x, W_w, W_b, out);
}